// Round 13
// baseline (116.547 us; speedup 1.0000x reference)
//
#include <hip/hip_runtime.h>

#define NX   192
#define NXY  (NX * NX)
#define LW   64              // lanes per row: one full wave per y-row
#define XA   48              // active lanes (4 x-outputs each -> 192 columns)
#define YB   4               // y rows (waves) per block
#define ZC   6               // z outputs per block
#define NTH  (LW * YB)       // 256 threads = 4 waves
#define GY   (NX / YB)       // 48
#define GZ   (NX / ZC)       // 32
#define NBLK (GY * GZ)       // 1536

static __device__ __forceinline__ float frcp(float x) {
#if __has_builtin(__builtin_amdgcn_rcpf)
    return __builtin_amdgcn_rcpf(x);
#else
    return 1.f / x;
#endif
}

// x-window: output o = x0+o needs cols (x0+o-1 .. x0+o+1); v holds cols
// x0-1..x0+2, s4 = col x0+3, s5 = col x0+4.
#define WIN(n, v, s4, s5)                    \
    n.x = v.x + v.y + v.z;                   \
    n.y = v.y + v.z + v.w;                   \
    n.z = v.z + v.w + s4;                    \
    n.w = v.w + s4 + s5;

#define NCCC(o)                                                            \
    {                                                                      \
        const float Is  = p0I.o  + p1I.o  + nI.o;                          \
        const float Js  = p0J.o  + p1J.o  + nJ.o;                          \
        const float IIs = p0II.o + p1II.o + nII.o;                         \
        const float JJs = p0JJ.o + p1JJ.o + nJJ.o;                         \
        const float IJs = p0IJ.o + p1IJ.o + nIJ.o;                         \
        const float uI = Is * inv27;                                       \
        const float uJ = Js * inv27;                                       \
        const float cross = fmaf(-uJ, Is, IJs);                            \
        const float Iv    = fmaf(-uI, Is, IIs);                            \
        const float Jv    = fmaf(-uJ, Js, JJs);                            \
        const float den   = fmaf(Iv, Jv, 1e-5f);                           \
        acc.o = fmaf(cross * cross, frcp(den), acc.o);                     \
    }

// one masked row's contribution to the 6 column stats.
#define ROWACC(a4, b4, s3a, s4a, s3b, s4b)                                  \
    vI.x += a4.x; vI.y += a4.y; vI.z += a4.z; vI.w += a4.w;                 \
    vJ.x += b4.x; vJ.y += b4.y; vJ.z += b4.z; vJ.w += b4.w;                 \
    vII.x = fmaf(a4.x, a4.x, vII.x); vII.y = fmaf(a4.y, a4.y, vII.y);       \
    vII.z = fmaf(a4.z, a4.z, vII.z); vII.w = fmaf(a4.w, a4.w, vII.w);       \
    vJJ.x = fmaf(b4.x, b4.x, vJJ.x); vJJ.y = fmaf(b4.y, b4.y, vJJ.y);       \
    vJJ.z = fmaf(b4.z, b4.z, vJJ.z); vJJ.w = fmaf(b4.w, b4.w, vJJ.w);       \
    vIJ.x = fmaf(a4.x, b4.x, vIJ.x); vIJ.y = fmaf(a4.y, b4.y, vIJ.y);       \
    vIJ.z = fmaf(a4.z, b4.z, vIJ.z); vIJ.w = fmaf(a4.w, b4.w, vIJ.w);       \
    vI4 += s3a; vI5 += s4a; vJ4 += s3b; vJ5 += s4b;                         \
    vII4 = fmaf(s3a, s3a, vII4); vII5 = fmaf(s4a, s4a, vII5);               \
    vJJ4 = fmaf(s3b, s3b, vJJ4); vJJ5 = fmaf(s4b, s4b, vJJ5);               \
    vIJ4 = fmaf(s3a, s3b, vIJ4); vIJ5 = fmaf(s4a, s4b, vIJ5);

// One z-slice: 6 float4 loads (one batch), edge columns via intra-wave
// shuffles (rows are wave-aligned so neighbors are true x-neighbors).
// For the interior template instantiation M0/M1/M2 are literal 1.f and all
// mask multiplies fold away at compile time (fmul x,1.0 -> x is exact).
#define DO_SLICE(ZB, M0, M1, M2, EMIT)                                      \
    {                                                                       \
        const float* pz = pred + (ZB);                                      \
        const float* tz = targ + (ZB);                                      \
        float4 a0 = *(const float4*)(pz + off0);                            \
        float4 b0 = *(const float4*)(tz + off0);                            \
        float4 a1 = *(const float4*)(pz + off1);                            \
        float4 b1 = *(const float4*)(tz + off1);                            \
        float4 a2 = *(const float4*)(pz + off2);                            \
        float4 b2 = *(const float4*)(tz + off2);                            \
        const float am0 = __shfl_up(a0.w, 1),  ap0 = __shfl_down(a0.x, 1);  \
        const float bm0 = __shfl_up(b0.w, 1),  bp0 = __shfl_down(b0.x, 1);  \
        const float am1 = __shfl_up(a1.w, 1),  ap1 = __shfl_down(a1.x, 1);  \
        const float bm1 = __shfl_up(b1.w, 1),  bp1 = __shfl_down(b1.x, 1);  \
        const float am2 = __shfl_up(a2.w, 1),  ap2 = __shfl_down(a2.x, 1);  \
        const float bm2 = __shfl_up(b2.w, 1),  bp2 = __shfl_down(b2.x, 1);  \
        const float M0_ = (M0), M1_ = (M1), M2_ = (M2);                     \
        const float em0 = M0_ * mxm, ep0 = M0_ * mxp;                       \
        const float em1 = M1_ * mxm, ep1 = M1_ * mxp;                       \
        const float em2 = M2_ * mxm, ep2 = M2_ * mxp;                       \
        float4 vI = zero4, vJ = zero4, vII = zero4, vJJ = zero4, vIJ = zero4;\
        float vI4 = 0.f, vI5 = 0.f, vJ4 = 0.f, vJ5 = 0.f;                   \
        float vII4 = 0.f, vII5 = 0.f, vJJ4 = 0.f, vJJ5 = 0.f;               \
        float vIJ4 = 0.f, vIJ5 = 0.f;                                       \
        {                                                                   \
            const float4 ra = make_float4(am0 * em0, a0.x * M0_, a0.y * M0_, a0.z * M0_); \
            const float4 rb = make_float4(bm0 * em0, b0.x * M0_, b0.y * M0_, b0.z * M0_); \
            ROWACC(ra, rb, a0.w * M0_, ap0 * ep0, b0.w * M0_, bp0 * ep0)    \
        }                                                                   \
        {                                                                   \
            const float4 ra = make_float4(am1 * em1, a1.x * M1_, a1.y * M1_, a1.z * M1_); \
            const float4 rb = make_float4(bm1 * em1, b1.x * M1_, b1.y * M1_, b1.z * M1_); \
            ROWACC(ra, rb, a1.w * M1_, ap1 * ep1, b1.w * M1_, bp1 * ep1)    \
        }                                                                   \
        {                                                                   \
            const float4 ra = make_float4(am2 * em2, a2.x * M2_, a2.y * M2_, a2.z * M2_); \
            const float4 rb = make_float4(bm2 * em2, b2.x * M2_, b2.y * M2_, b2.z * M2_); \
            ROWACC(ra, rb, a2.w * M2_, ap2 * ep2, b2.w * M2_, bp2 * ep2)    \
        }                                                                   \
        float4 nI, nJ, nII, nJJ, nIJ;                                       \
        WIN(nI,  vI,  vI4,  vI5)                                            \
        WIN(nJ,  vJ,  vJ4,  vJ5)                                            \
        WIN(nII, vII, vII4, vII5)                                           \
        WIN(nJJ, vJJ, vJJ4, vJJ5)                                           \
        WIN(nIJ, vIJ, vIJ4, vIJ5)                                           \
        if (EMIT) { NCCC(x) NCCC(y) NCCC(z) NCCC(w) }                       \
        p0I = p1I; p0J = p1J; p0II = p1II; p0JJ = p1JJ; p0IJ = p1IJ;        \
        p1I = nI;  p1J = nJ;  p1II = nII;  p1JJ = nJJ;  p1IJ = nIJ;         \
    }

// YI = y-interior block (no y-boundary rows), ZI = z-interior block.
// Interior instantiation folds all row/z masks to nothing (~20% VALU cut);
// 88% of blocks take the interior path (uniform branch, no divergence).
template<bool YI, bool ZI>
static __device__ __forceinline__ float
lncc_body(const float* __restrict__ pred, const float* __restrict__ targ) {
    const int k   = threadIdx.x;               // 0..63
    const int ke  = (k < XA) ? k : XA - 1;     // clamped for idle lanes
    const int x0  = 4 * ke;
    const int y  = blockIdx.y * YB + threadIdx.y;
    const int z0 = blockIdx.z * ZC;

    const int ym = YI ? (y - 1) : ((y > 0) ? y - 1 : 0);
    const int yp = YI ? (y + 1) : ((y < NX - 1) ? y + 1 : y);
    const int off0 = ym * NX + x0;
    const int off1 = y  * NX + x0;
    const int off2 = yp * NX + x0;

    const float fm0 = YI ? 1.f : ((y > 0) ? 1.f : 0.f);
    const float fm2 = YI ? 1.f : ((y < NX - 1) ? 1.f : 0.f);
    const float mxm = (k > 0) ? 1.f : 0.f;
    const float mxp = (k < XA - 1) ? 1.f : 0.f;
    const float zmA = ZI ? 1.f : ((z0 > 0) ? 1.f : 0.f);
    const float zmB = ZI ? 1.f : ((z0 + ZC < NX) ? 1.f : 0.f);
    const int   zb0 = (ZI ? (z0 - 1) : ((z0 > 0) ? z0 - 1 : 0)) * NXY;
    const int   zbL = (ZI ? (z0 + ZC) : ((z0 + ZC < NX) ? z0 + ZC : NX - 1)) * NXY;

    const float inv27 = 1.f / 27.f;
    const float4 zero4 = make_float4(0.f, 0.f, 0.f, 0.f);
    float4 p0I = zero4, p0J = zero4, p0II = zero4, p0JJ = zero4, p0IJ = zero4;
    float4 p1I = zero4, p1J = zero4, p1II = zero4, p1JJ = zero4, p1IJ = zero4;
    float4 acc = zero4;

    // 8-step schedule: slice z = z0-1+s; emit for s>=2 (output z0+s-2)
    DO_SLICE(zb0,            fm0 * zmA, zmA, fm2 * zmA, 0)   // s=0: z0-1
    DO_SLICE((z0    ) * NXY, fm0,       1.f, fm2,       0)   // s=1
    DO_SLICE((z0 + 1) * NXY, fm0,       1.f, fm2,       1)   // s=2
    DO_SLICE((z0 + 2) * NXY, fm0,       1.f, fm2,       1)   // s=3
    DO_SLICE((z0 + 3) * NXY, fm0,       1.f, fm2,       1)   // s=4
    DO_SLICE((z0 + 4) * NXY, fm0,       1.f, fm2,       1)   // s=5
    DO_SLICE((z0 + 5) * NXY, fm0,       1.f, fm2,       1)   // s=6
    DO_SLICE(zbL,            fm0 * zmB, zmB, fm2 * zmB, 1)   // s=7: z0+ZC

    return acc.x + acc.y + acc.z + acc.w;
}

__global__ __launch_bounds__(NTH)
void lncc_main(const float* __restrict__ pred, const float* __restrict__ targ,
               double* __restrict__ partial) {
    __shared__ float wred[NTH / 64];

    const bool yi = (blockIdx.y > 0) && (blockIdx.y < GY - 1);
    const bool zi = (blockIdx.z > 0) && (blockIdx.z < GZ - 1);

    float v;
    if (yi && zi) v = lncc_body<true, true>(pred, targ);     // 88% of blocks
    else          v = lncc_body<false, false>(pred, targ);

    const float lane_act = (threadIdx.x < XA) ? 1.f : 0.f;
    v *= lane_act;
#pragma unroll
    for (int off = 32; off > 0; off >>= 1) v += __shfl_down(v, off);
    const int tid = threadIdx.y * LW + threadIdx.x;
    if ((tid & 63) == 0) wred[tid >> 6] = v;
    __syncthreads();
    if (tid == 0) {
        double t = 0.0;
#pragma unroll
        for (int i = 0; i < NTH / 64; ++i) t += (double)wred[i];
        partial[blockIdx.z * GY + blockIdx.y] = t;
    }
}

__global__ __launch_bounds__(256)
void lncc_reduce(const double* __restrict__ partial, float* __restrict__ out) {
    __shared__ double dred[4];
    double sum = 0.0;
    for (int i = threadIdx.x; i < NBLK; i += 256) sum += partial[i];
#pragma unroll
    for (int off = 32; off > 0; off >>= 1) sum += __shfl_down(sum, off);
    if ((threadIdx.x & 63) == 0) dred[threadIdx.x >> 6] = sum;
    __syncthreads();
    if (threadIdx.x == 0) {
        const double n = (double)NX * NX * NX;
        out[0] = (float)(-(dred[0] + dred[1] + dred[2] + dred[3]) / n);
    }
}

extern "C" void kernel_launch(void* const* d_in, const int* in_sizes, int n_in,
                              void* d_out, int out_size, void* d_ws, size_t ws_size,
                              hipStream_t stream) {
    const float* pred = (const float*)d_in[0];
    const float* targ = (const float*)d_in[1];
    double* partial = (double*)d_ws;
    float* out = (float*)d_out;

    dim3 grid(1, GY, GZ);                 // 1 x 48 x 32 = 1536 blocks
    dim3 block(LW, YB);                   // 64 x 4 = 256 threads (4 waves)
    lncc_main<<<grid, block, 0, stream>>>(pred, targ, partial);
    lncc_reduce<<<1, 256, 0, stream>>>(partial, out);
}

// Round 14
// 98.162 us; speedup vs baseline: 1.1873x; 1.1873x over previous
//
#include <hip/hip_runtime.h>

#define NX   192
#define NXY  (NX * NX)
#define LW   64              // lanes per row: one full wave per y-row
#define XA   48              // active lanes (4 x-outputs each -> 192 columns)
#define YB   4               // y rows (waves) per block
#define ZC   6               // z outputs per block
#define NTH  (LW * YB)       // 256 threads = 4 waves
#define GY   (NX / YB)       // 48
#define GZ   (NX / ZC)       // 32
#define NBLK (GY * GZ)       // 1536

static __device__ __forceinline__ float frcp(float x) {
#if __has_builtin(__builtin_amdgcn_rcpf)
    return __builtin_amdgcn_rcpf(x);
#else
    return 1.f / x;
#endif
}

// x-window: output o = x0+o needs cols (x0+o-1 .. x0+o+1); v holds cols
// x0-1..x0+2, s4 = col x0+3, s5 = col x0+4.
#define WIN(n, v, s4, s5)                    \
    n.x = v.x + v.y + v.z;                   \
    n.y = v.y + v.z + v.w;                   \
    n.z = v.z + v.w + s4;                    \
    n.w = v.w + s4 + s5;

#define NCCC(o)                                                            \
    {                                                                      \
        const float Is  = p0I.o  + p1I.o  + nI.o;                          \
        const float Js  = p0J.o  + p1J.o  + nJ.o;                          \
        const float IIs = p0II.o + p1II.o + nII.o;                         \
        const float JJs = p0JJ.o + p1JJ.o + nJJ.o;                         \
        const float IJs = p0IJ.o + p1IJ.o + nIJ.o;                         \
        const float uI = Is * inv27;                                       \
        const float uJ = Js * inv27;                                       \
        const float cross = fmaf(-uJ, Is, IJs);                            \
        const float Iv    = fmaf(-uI, Is, IIs);                            \
        const float Jv    = fmaf(-uJ, Js, JJs);                            \
        const float den   = fmaf(Iv, Jv, 1e-5f);                           \
        acc.o = fmaf(cross * cross, frcp(den), acc.o);                     \
    }

// one masked row's contribution to the 6 column stats.
#define ROWACC(a4, b4, s3a, s4a, s3b, s4b)                                  \
    vI.x += a4.x; vI.y += a4.y; vI.z += a4.z; vI.w += a4.w;                 \
    vJ.x += b4.x; vJ.y += b4.y; vJ.z += b4.z; vJ.w += b4.w;                 \
    vII.x = fmaf(a4.x, a4.x, vII.x); vII.y = fmaf(a4.y, a4.y, vII.y);       \
    vII.z = fmaf(a4.z, a4.z, vII.z); vII.w = fmaf(a4.w, a4.w, vII.w);       \
    vJJ.x = fmaf(b4.x, b4.x, vJJ.x); vJJ.y = fmaf(b4.y, b4.y, vJJ.y);       \
    vJJ.z = fmaf(b4.z, b4.z, vJJ.z); vJJ.w = fmaf(b4.w, b4.w, vJJ.w);       \
    vIJ.x = fmaf(a4.x, b4.x, vIJ.x); vIJ.y = fmaf(a4.y, b4.y, vIJ.y);       \
    vIJ.z = fmaf(a4.z, b4.z, vIJ.z); vIJ.w = fmaf(a4.w, b4.w, vIJ.w);       \
    vI4 += s3a; vI5 += s4a; vJ4 += s3b; vJ5 += s4b;                         \
    vII4 = fmaf(s3a, s3a, vII4); vII5 = fmaf(s4a, s4a, vII5);               \
    vJJ4 = fmaf(s3b, s3b, vJJ4); vJJ5 = fmaf(s4b, s4b, vJJ5);               \
    vIJ4 = fmaf(s3a, s3b, vIJ4); vIJ5 = fmaf(s4a, s4b, vIJ5);

// One z-slice: 6 float4 loads (one batch), edge columns via intra-wave
// shuffles. Rows are wave-aligned (blockDim.x == 64) so lane k-1 / k+1 are
// ALWAYS the true x-neighbors; k=0 / k>=47 edge lanes are mask-zeroed and
// lanes 48-63 are fully masked out of the accumulator.
#define DO_SLICE(ZB, M0, M1, M2, EMIT)                                      \
    {                                                                       \
        const float* pz = pred + (ZB);                                      \
        const float* tz = targ + (ZB);                                      \
        float4 a0 = *(const float4*)(pz + off0);                            \
        float4 b0 = *(const float4*)(tz + off0);                            \
        float4 a1 = *(const float4*)(pz + off1);                            \
        float4 b1 = *(const float4*)(tz + off1);                            \
        float4 a2 = *(const float4*)(pz + off2);                            \
        float4 b2 = *(const float4*)(tz + off2);                            \
        const float am0 = __shfl_up(a0.w, 1),  ap0 = __shfl_down(a0.x, 1);  \
        const float bm0 = __shfl_up(b0.w, 1),  bp0 = __shfl_down(b0.x, 1);  \
        const float am1 = __shfl_up(a1.w, 1),  ap1 = __shfl_down(a1.x, 1);  \
        const float bm1 = __shfl_up(b1.w, 1),  bp1 = __shfl_down(b1.x, 1);  \
        const float am2 = __shfl_up(a2.w, 1),  ap2 = __shfl_down(a2.x, 1);  \
        const float bm2 = __shfl_up(b2.w, 1),  bp2 = __shfl_down(b2.x, 1);  \
        const float M0_ = (M0), M1_ = (M1), M2_ = (M2);                     \
        const float em0 = M0_ * mxm, ep0 = M0_ * mxp;                       \
        const float em1 = M1_ * mxm, ep1 = M1_ * mxp;                       \
        const float em2 = M2_ * mxm, ep2 = M2_ * mxp;                       \
        float4 vI = zero4, vJ = zero4, vII = zero4, vJJ = zero4, vIJ = zero4;\
        float vI4 = 0.f, vI5 = 0.f, vJ4 = 0.f, vJ5 = 0.f;                   \
        float vII4 = 0.f, vII5 = 0.f, vJJ4 = 0.f, vJJ5 = 0.f;               \
        float vIJ4 = 0.f, vIJ5 = 0.f;                                       \
        {                                                                   \
            const float4 ra = make_float4(am0 * em0, a0.x * M0_, a0.y * M0_, a0.z * M0_); \
            const float4 rb = make_float4(bm0 * em0, b0.x * M0_, b0.y * M0_, b0.z * M0_); \
            ROWACC(ra, rb, a0.w * M0_, ap0 * ep0, b0.w * M0_, bp0 * ep0)    \
        }                                                                   \
        {                                                                   \
            const float4 ra = make_float4(am1 * em1, a1.x * M1_, a1.y * M1_, a1.z * M1_); \
            const float4 rb = make_float4(bm1 * em1, b1.x * M1_, b1.y * M1_, b1.z * M1_); \
            ROWACC(ra, rb, a1.w * M1_, ap1 * ep1, b1.w * M1_, bp1 * ep1)    \
        }                                                                   \
        {                                                                   \
            const float4 ra = make_float4(am2 * em2, a2.x * M2_, a2.y * M2_, a2.z * M2_); \
            const float4 rb = make_float4(bm2 * em2, b2.x * M2_, b2.y * M2_, b2.z * M2_); \
            ROWACC(ra, rb, a2.w * M2_, ap2 * ep2, b2.w * M2_, bp2 * ep2)    \
        }                                                                   \
        float4 nI, nJ, nII, nJJ, nIJ;                                       \
        WIN(nI,  vI,  vI4,  vI5)                                            \
        WIN(nJ,  vJ,  vJ4,  vJ5)                                            \
        WIN(nII, vII, vII4, vII5)                                           \
        WIN(nJJ, vJJ, vJJ4, vJJ5)                                           \
        WIN(nIJ, vIJ, vIJ4, vIJ5)                                           \
        if (EMIT) { NCCC(x) NCCC(y) NCCC(z) NCCC(w) }                       \
        p0I = p1I; p0J = p1J; p0II = p1II; p0JJ = p1JJ; p0IJ = p1IJ;        \
        p1I = nI;  p1J = nJ;  p1II = nII;  p1JJ = nJJ;  p1IJ = nIJ;         \
    }

// Register-only LNCC, branchless hot path, wave-aligned rows (64 lanes/row,
// 48 active). Single code path (round 13 proved a second inlined template
// path unions register frames: VGPR 64->160, occupancy /3). Two-kernel
// reduction (round 11: fused atomic+fence reduction costs ~48 us tail).
__global__ __launch_bounds__(NTH)
void lncc_main(const float* __restrict__ pred, const float* __restrict__ targ,
               double* __restrict__ partial) {
    __shared__ float wred[NTH / 64];

    const int k   = threadIdx.x;               // 0..63 (lane within the row-wave)
    const int ke  = (k < XA) ? k : XA - 1;     // clamped for idle lanes
    const int x0  = 4 * ke;
    const int y  = blockIdx.y * YB + threadIdx.y;
    const int z0 = blockIdx.z * ZC;

    // pre-clamped row offsets (always in-bounds)
    const int ym = (y > 0) ? y - 1 : 0;
    const int yp = (y < NX - 1) ? y + 1 : y;
    const int off0 = ym * NX + x0;
    const int off1 = y  * NX + x0;
    const int off2 = yp * NX + x0;

    // 0/1 masks for the padding contributions
    const float fm0 = (y > 0) ? 1.f : 0.f;
    const float fm2 = (y < NX - 1) ? 1.f : 0.f;
    const float mxm = (k > 0) ? 1.f : 0.f;         // k=0 volume edge
    const float mxp = (k < XA - 1) ? 1.f : 0.f;    // k>=47: edge or idle lane
    const float lane_act = (k < XA) ? 1.f : 0.f;   // idle-lane kill switch
    const float zmA = (z0 > 0) ? 1.f : 0.f;            // step 0 z-mask
    const float zmB = (z0 + ZC < NX) ? 1.f : 0.f;      // last step z-mask
    const int   zb0 = ((z0 > 0) ? z0 - 1 : 0) * NXY;   // clamped z bases
    const int   zb7 = ((z0 + ZC < NX) ? z0 + ZC : NX - 1) * NXY;

    const float inv27 = 1.f / 27.f;
    const float4 zero4 = make_float4(0.f, 0.f, 0.f, 0.f);
    float4 p0I = zero4, p0J = zero4, p0II = zero4, p0JJ = zero4, p0IJ = zero4;
    float4 p1I = zero4, p1J = zero4, p1II = zero4, p1JJ = zero4, p1IJ = zero4;
    float4 acc = zero4;

    // 8-step schedule: slice z = z0-1+s; emit for s>=2 (output z0+s-2)
    DO_SLICE(zb0,            fm0 * zmA, zmA, fm2 * zmA, 0)   // s=0
    DO_SLICE((z0    ) * NXY, fm0,       1.f, fm2,       0)   // s=1
    DO_SLICE((z0 + 1) * NXY, fm0,       1.f, fm2,       1)   // s=2
    DO_SLICE((z0 + 2) * NXY, fm0,       1.f, fm2,       1)   // s=3
    DO_SLICE((z0 + 3) * NXY, fm0,       1.f, fm2,       1)   // s=4
    DO_SLICE((z0 + 4) * NXY, fm0,       1.f, fm2,       1)   // s=5
    DO_SLICE((z0 + 5) * NXY, fm0,       1.f, fm2,       1)   // s=6
    DO_SLICE(zb7,            fm0 * zmB, zmB, fm2 * zmB, 1)   // s=7

    // ---- block reduction -> one double partial per block ----
    float v = (acc.x + acc.y + acc.z + acc.w) * lane_act;
#pragma unroll
    for (int off = 32; off > 0; off >>= 1) v += __shfl_down(v, off);
    const int tid = threadIdx.y * LW + threadIdx.x;
    if ((tid & 63) == 0) wred[tid >> 6] = v;
    __syncthreads();
    if (tid == 0) {
        double t = 0.0;
#pragma unroll
        for (int i = 0; i < NTH / 64; ++i) t += (double)wred[i];
        partial[blockIdx.z * GY + blockIdx.y] = t;
    }
}

__global__ __launch_bounds__(256)
void lncc_reduce(const double* __restrict__ partial, float* __restrict__ out) {
    __shared__ double dred[4];
    double sum = 0.0;
    for (int i = threadIdx.x; i < NBLK; i += 256) sum += partial[i];
#pragma unroll
    for (int off = 32; off > 0; off >>= 1) sum += __shfl_down(sum, off);
    if ((threadIdx.x & 63) == 0) dred[threadIdx.x >> 6] = sum;
    __syncthreads();
    if (threadIdx.x == 0) {
        const double n = (double)NX * NX * NX;
        out[0] = (float)(-(dred[0] + dred[1] + dred[2] + dred[3]) / n);
    }
}

extern "C" void kernel_launch(void* const* d_in, const int* in_sizes, int n_in,
                              void* d_out, int out_size, void* d_ws, size_t ws_size,
                              hipStream_t stream) {
    const float* pred = (const float*)d_in[0];
    const float* targ = (const float*)d_in[1];
    double* partial = (double*)d_ws;
    float* out = (float*)d_out;

    dim3 grid(1, GY, GZ);                 // 1 x 48 x 32 = 1536 blocks
    dim3 block(LW, YB);                   // 64 x 4 = 256 threads (4 waves)
    lncc_main<<<grid, block, 0, stream>>>(pred, targ, partial);
    lncc_reduce<<<1, 256, 0, stream>>>(partial, out);
}